// Round 1
// baseline (14117.757 us; speedup 1.0000x reference)
//
#include <hip/hip_runtime.h>

// Sizes are fixed by the problem.
#define NN 1048576   // nodes
#define NE 8388608   // edges
#define NG 32768     // graphs
#define DD 9         // emb dim
#define HH 18        // hidden
#define BN_EPS 1e-5f

// stats buffer offsets (floats)
#define SUM1    0
#define SQ1     18
#define SUM2    36
#define SQ2     45
#define SCALE1  54
#define SHIFT1  72
#define SCALE2  90
#define SHIFT2  99
#define VSUM1   108
#define VSQ1    126
#define VSUM2   144
#define VSQ2    153
#define VSCALE1 162
#define VSHIFT1 180
#define VSCALE2 198
#define VSHIFT2 207
#define STATS_FLOATS 256

__device__ __forceinline__ float waveReduce(float v) {
#pragma unroll
  for (int off = 32; off > 0; off >>= 1) v += __shfl_down(v, off, 64);
  return v;
}

// h[n,:] = sum_f atom_emb[f, x[n,f], :]
__global__ void k_atom(const float* __restrict__ atom_emb, const int* __restrict__ x,
                       float* __restrict__ h) {
  int n = blockIdx.x * 256 + threadIdx.x;
  int xi[9];
#pragma unroll
  for (int f = 0; f < 9; ++f) xi[f] = x[(size_t)n * 9 + f];
  float acc[DD] = {0.f,0.f,0.f,0.f,0.f,0.f,0.f,0.f,0.f};
#pragma unroll
  for (int f = 0; f < 9; ++f) {
    const float* row = atom_emb + ((size_t)f * 119 + xi[f]) * DD;
#pragma unroll
    for (int d = 0; d < DD; ++d) acc[d] += row[d];
  }
#pragma unroll
  for (int d = 0; d < DD; ++d) h[(size_t)n * DD + d] = acc[d];
}

// h_in[n] = h[n] + vn[batch[n]];  optionally vnsum[batch[n]] += h_in[n]
__global__ void k_hin(const float* __restrict__ h, const float* __restrict__ vn,
                      const int* __restrict__ batch, float* __restrict__ h_in,
                      float* __restrict__ vnsum, int do_vnsum) {
  int n = blockIdx.x * 256 + threadIdx.x;
  int g = batch[n];
  float v[DD];
#pragma unroll
  for (int d = 0; d < DD; ++d) {
    v[d] = h[(size_t)n * DD + d] + vn[(size_t)g * DD + d];
    h_in[(size_t)n * DD + d] = v[d];
  }
  if (do_vnsum) {
#pragma unroll
    for (int d = 0; d < DD; ++d) atomicAdd(&vnsum[(size_t)g * DD + d], v[d]);
  }
}

// msg = relu(h_in[src] + bond_emb); X[dst] += msg
__global__ void k_edge(const float* __restrict__ h_in, const int* __restrict__ ei,
                       const int* __restrict__ ea, const float* __restrict__ bond,
                       float* __restrict__ X) {
  __shared__ float B[3 * 6 * DD];  // 162 floats
  for (int i = threadIdx.x; i < 3 * 6 * DD; i += 256) B[i] = bond[i];
  __syncthreads();
  int e = blockIdx.x * 256 + threadIdx.x;
  int s = ei[e];
  int t = ei[NE + e];
  int a0 = ea[(size_t)e * 3 + 0];
  int a1 = ea[(size_t)e * 3 + 1];
  int a2 = ea[(size_t)e * 3 + 2];
  const float* b0 = B + (0 * 6 + a0) * DD;
  const float* b1 = B + (1 * 6 + a1) * DD;
  const float* b2 = B + (2 * 6 + a2) * DD;
  const float* hs = h_in + (size_t)s * DD;
  float* xt = X + (size_t)t * DD;
#pragma unroll
  for (int d = 0; d < DD; ++d) {
    float m = hs[d] + b0[d] + b1[d] + b2[d];
    m = m > 0.f ? m : 0.f;
    atomicAdd(&xt[d], m);
  }
}

// z = (1+eps)*h_in + aggr (in place into X); t1 = z@W1+b1; accumulate BN1 stats
__global__ void k_partA(float* __restrict__ X, const float* __restrict__ h_in,
                        const float* __restrict__ W1l, const float* __restrict__ b1l,
                        const float* __restrict__ epsp, float* __restrict__ stats) {
  __shared__ float sW[DD * HH], sb[HH], ssum[HH], ssq[HH];
  for (int i = threadIdx.x; i < DD * HH; i += 256) sW[i] = W1l[i];
  if (threadIdx.x < HH) {
    sb[threadIdx.x] = b1l[threadIdx.x];
    ssum[threadIdx.x] = 0.f;
    ssq[threadIdx.x] = 0.f;
  }
  __syncthreads();
  int n = blockIdx.x * 256 + threadIdx.x;
  float eps1 = 1.0f + epsp[0];
  float z[DD];
#pragma unroll
  for (int d = 0; d < DD; ++d) {
    float zz = eps1 * h_in[(size_t)n * DD + d] + X[(size_t)n * DD + d];
    z[d] = zz;
    X[(size_t)n * DD + d] = zz;
  }
  int lane0 = ((threadIdx.x & 63) == 0);
#pragma unroll
  for (int j = 0; j < HH; ++j) {
    float a = sb[j];
#pragma unroll
    for (int d = 0; d < DD; ++d) a += z[d] * sW[d * HH + j];
    float rs = waveReduce(a);
    float rq = waveReduce(a * a);
    if (lane0) { atomicAdd(&ssum[j], rs); atomicAdd(&ssq[j], rq); }
  }
  __syncthreads();
  if (threadIdx.x < HH) {
    atomicAdd(&stats[SUM1 + threadIdx.x], ssum[threadIdx.x]);
    atomicAdd(&stats[SQ1 + threadIdx.x], ssq[threadIdx.x]);
  }
}

// generic BN finalize: scale = g*rsqrt(var+eps), shift = b - mean*scale
__global__ void k_bnfin(float* __restrict__ stats, const float* __restrict__ g,
                        const float* __restrict__ b, int C, float invN,
                        int sum_off, int sq_off, int scale_off, int shift_off) {
  int c = threadIdx.x;
  if (c >= C) return;
  float mean = stats[sum_off + c] * invN;
  float var = stats[sq_off + c] * invN - mean * mean;
  float inv = rsqrtf(var + BN_EPS);
  float sc = g[c] * inv;
  stats[scale_off + c] = sc;
  stats[shift_off + c] = b[c] - mean * sc;
}

// recompute t1 = z@W1+b1; t = relu(bn1(t1)); z2 = t@W2+b2 -> Y; BN2 stats
__global__ void k_partB(const float* __restrict__ X, float* __restrict__ Y,
                        const float* __restrict__ W1l, const float* __restrict__ b1l,
                        const float* __restrict__ W2l, const float* __restrict__ b2l,
                        const float* __restrict__ stats, float* __restrict__ statw) {
  __shared__ float sW1[DD * HH], sW2[HH * DD], sb1[HH], sb2[DD];
  __shared__ float sc1[HH], sh1[HH], ssum[DD], ssq[DD];
  for (int i = threadIdx.x; i < DD * HH; i += 256) sW1[i] = W1l[i];
  for (int i = threadIdx.x; i < HH * DD; i += 256) sW2[i] = W2l[i];
  if (threadIdx.x < HH) {
    sb1[threadIdx.x] = b1l[threadIdx.x];
    sc1[threadIdx.x] = stats[SCALE1 + threadIdx.x];
    sh1[threadIdx.x] = stats[SHIFT1 + threadIdx.x];
  }
  if (threadIdx.x < DD) {
    sb2[threadIdx.x] = b2l[threadIdx.x];
    ssum[threadIdx.x] = 0.f;
    ssq[threadIdx.x] = 0.f;
  }
  __syncthreads();
  int n = blockIdx.x * 256 + threadIdx.x;
  float z[DD];
#pragma unroll
  for (int d = 0; d < DD; ++d) z[d] = X[(size_t)n * DD + d];
  float t[HH];
#pragma unroll
  for (int j = 0; j < HH; ++j) {
    float a = sb1[j];
#pragma unroll
    for (int d = 0; d < DD; ++d) a += z[d] * sW1[d * HH + j];
    a = a * sc1[j] + sh1[j];
    t[j] = a > 0.f ? a : 0.f;
  }
  int lane0 = ((threadIdx.x & 63) == 0);
#pragma unroll
  for (int d = 0; d < DD; ++d) {
    float a = sb2[d];
#pragma unroll
    for (int j = 0; j < HH; ++j) a += t[j] * sW2[j * DD + d];
    Y[(size_t)n * DD + d] = a;
    float rs = waveReduce(a);
    float rq = waveReduce(a * a);
    if (lane0) { atomicAdd(&ssum[d], rs); atomicAdd(&ssq[d], rq); }
  }
  __syncthreads();
  if (threadIdx.x < DD) {
    atomicAdd(&statw[SUM2 + threadIdx.x], ssum[threadIdx.x]);
    atomicAdd(&statw[SQ2 + threadIdx.x], ssq[threadIdx.x]);
  }
}

// h = bn2(z2) [relu] + h_in; on last layer accumulate column sums into out
__global__ void k_partC(const float* __restrict__ Y, const float* __restrict__ h_in,
                        float* __restrict__ h, const float* __restrict__ stats,
                        int do_relu, float* __restrict__ out) {
  __shared__ float sc[DD], sh[DD], ssum[DD];
  if (threadIdx.x < DD) {
    sc[threadIdx.x] = stats[SCALE2 + threadIdx.x];
    sh[threadIdx.x] = stats[SHIFT2 + threadIdx.x];
    ssum[threadIdx.x] = 0.f;
  }
  __syncthreads();
  int n = blockIdx.x * 256 + threadIdx.x;
  float hv[DD];
#pragma unroll
  for (int d = 0; d < DD; ++d) {
    float z = Y[(size_t)n * DD + d] * sc[d] + sh[d];
    if (do_relu) z = z > 0.f ? z : 0.f;
    hv[d] = z + h_in[(size_t)n * DD + d];
    h[(size_t)n * DD + d] = hv[d];
  }
  if (out != nullptr) {
    int lane0 = ((threadIdx.x & 63) == 0);
#pragma unroll
    for (int d = 0; d < DD; ++d) {
      float r = waveReduce(hv[d]);
      if (lane0) atomicAdd(&ssum[d], r);
    }
    __syncthreads();
    if (threadIdx.x < DD) atomicAdd(&out[threadIdx.x], ssum[threadIdx.x]);
  }
}

// VN MLP stage 1: row = vnsum[g]+vn[g]; t1 = row@vnW1+vnb1 -> vt1; stats
__global__ void k_vnA(const float* __restrict__ vnsum, const float* __restrict__ vn,
                      float* __restrict__ vt1, const float* __restrict__ W1l,
                      const float* __restrict__ b1l, float* __restrict__ stats) {
  __shared__ float sW[DD * HH], sb[HH], ssum[HH], ssq[HH];
  for (int i = threadIdx.x; i < DD * HH; i += 256) sW[i] = W1l[i];
  if (threadIdx.x < HH) {
    sb[threadIdx.x] = b1l[threadIdx.x];
    ssum[threadIdx.x] = 0.f;
    ssq[threadIdx.x] = 0.f;
  }
  __syncthreads();
  int g = blockIdx.x * 256 + threadIdx.x;
  float r[DD];
#pragma unroll
  for (int d = 0; d < DD; ++d)
    r[d] = vnsum[(size_t)g * DD + d] + vn[(size_t)g * DD + d];
  int lane0 = ((threadIdx.x & 63) == 0);
#pragma unroll
  for (int j = 0; j < HH; ++j) {
    float a = sb[j];
#pragma unroll
    for (int d = 0; d < DD; ++d) a += r[d] * sW[d * HH + j];
    vt1[(size_t)g * HH + j] = a;
    float rs = waveReduce(a);
    float rq = waveReduce(a * a);
    if (lane0) { atomicAdd(&ssum[j], rs); atomicAdd(&ssq[j], rq); }
  }
  __syncthreads();
  if (threadIdx.x < HH) {
    atomicAdd(&stats[VSUM1 + threadIdx.x], ssum[threadIdx.x]);
    atomicAdd(&stats[VSQ1 + threadIdx.x], ssq[threadIdx.x]);
  }
}

// VN stage 2: t = relu(bn1(vt1)); t2 = t@vnW2+vnb2 -> vt2; stats
__global__ void k_vnB(const float* __restrict__ vt1, float* __restrict__ vt2,
                      const float* __restrict__ W2l, const float* __restrict__ b2l,
                      float* __restrict__ stats) {
  __shared__ float sW2[HH * DD], sb2[DD], sc1[HH], sh1[HH], ssum[DD], ssq[DD];
  for (int i = threadIdx.x; i < HH * DD; i += 256) sW2[i] = W2l[i];
  if (threadIdx.x < HH) {
    sc1[threadIdx.x] = stats[VSCALE1 + threadIdx.x];
    sh1[threadIdx.x] = stats[VSHIFT1 + threadIdx.x];
  }
  if (threadIdx.x < DD) {
    sb2[threadIdx.x] = b2l[threadIdx.x];
    ssum[threadIdx.x] = 0.f;
    ssq[threadIdx.x] = 0.f;
  }
  __syncthreads();
  int g = blockIdx.x * 256 + threadIdx.x;
  float t[HH];
#pragma unroll
  for (int j = 0; j < HH; ++j) {
    float a = vt1[(size_t)g * HH + j] * sc1[j] + sh1[j];
    t[j] = a > 0.f ? a : 0.f;
  }
  int lane0 = ((threadIdx.x & 63) == 0);
#pragma unroll
  for (int d = 0; d < DD; ++d) {
    float a = sb2[d];
#pragma unroll
    for (int j = 0; j < HH; ++j) a += t[j] * sW2[j * DD + d];
    vt2[(size_t)g * DD + d] = a;
    float rs = waveReduce(a);
    float rq = waveReduce(a * a);
    if (lane0) { atomicAdd(&ssum[d], rs); atomicAdd(&ssq[d], rq); }
  }
  __syncthreads();
  if (threadIdx.x < DD) {
    atomicAdd(&stats[VSUM2 + threadIdx.x], ssum[threadIdx.x]);
    atomicAdd(&stats[VSQ2 + threadIdx.x], ssq[threadIdx.x]);
  }
}

// VN stage 3: vn += relu(bn2(vt2))
__global__ void k_vnC(const float* __restrict__ vt2, float* __restrict__ vn,
                      const float* __restrict__ stats) {
  __shared__ float sc[DD], sh[DD];
  if (threadIdx.x < DD) {
    sc[threadIdx.x] = stats[VSCALE2 + threadIdx.x];
    sh[threadIdx.x] = stats[VSHIFT2 + threadIdx.x];
  }
  __syncthreads();
  int g = blockIdx.x * 256 + threadIdx.x;
#pragma unroll
  for (int d = 0; d < DD; ++d) {
    float v = vt2[(size_t)g * DD + d] * sc[d] + sh[d];
    v = v > 0.f ? v : 0.f;
    vn[(size_t)g * DD + d] += v;
  }
}

extern "C" void kernel_launch(void* const* d_in, const int* in_sizes, int n_in,
                              void* d_out, int out_size, void* d_ws, size_t ws_size,
                              hipStream_t stream) {
  const float* atom_emb = (const float*)d_in[0];
  const float* bond_emb = (const float*)d_in[1];
  const float* eps_gin  = (const float*)d_in[2];
  const float* W1   = (const float*)d_in[3];
  const float* b1   = (const float*)d_in[4];
  const float* bn1_g = (const float*)d_in[5];
  const float* bn1_b = (const float*)d_in[6];
  const float* W2   = (const float*)d_in[7];
  const float* b2   = (const float*)d_in[8];
  const float* bno_g = (const float*)d_in[9];
  const float* bno_b = (const float*)d_in[10];
  const float* vnW1 = (const float*)d_in[11];
  const float* vnb1 = (const float*)d_in[12];
  const float* vnbn1_g = (const float*)d_in[13];
  const float* vnbn1_b = (const float*)d_in[14];
  const float* vnW2 = (const float*)d_in[15];
  const float* vnb2 = (const float*)d_in[16];
  const float* vnbn2_g = (const float*)d_in[17];
  const float* vnbn2_b = (const float*)d_in[18];
  const int* x          = (const int*)d_in[19];
  const int* edge_index = (const int*)d_in[20];
  const int* edge_attr  = (const int*)d_in[21];
  const int* batch      = (const int*)d_in[22];
  float* out = (float*)d_out;

  // workspace layout (floats); total ~39.3M floats ~ 157 MB
  float* h     = (float*)d_ws;
  float* h_in  = h    + (size_t)NN * DD;
  float* X     = h_in + (size_t)NN * DD;   // aggr, then z (in place)
  float* Y     = X    + (size_t)NN * DD;   // z2
  float* vn    = Y    + (size_t)NN * DD;   // NG*DD
  float* vnsum = vn    + (size_t)NG * DD;
  float* vt1   = vnsum + (size_t)NG * DD;  // NG*HH
  float* vt2   = vt1   + (size_t)NG * HH;
  float* stats = vt2   + (size_t)NG * DD;  // STATS_FLOATS

  hipMemsetAsync(vn, 0, (size_t)NG * DD * sizeof(float), stream);
  hipMemsetAsync(out, 0, (size_t)DD * sizeof(float), stream);
  k_atom<<<NN / 256, 256, 0, stream>>>(atom_emb, x, h);

  for (int l = 0; l < 3; ++l) {
    int has_vn = (l < 2) ? 1 : 0;
    hipMemsetAsync(X, 0, (size_t)NN * DD * sizeof(float), stream);
    hipMemsetAsync(stats, 0, STATS_FLOATS * sizeof(float), stream);
    if (has_vn)
      hipMemsetAsync(vnsum, 0, (size_t)NG * DD * sizeof(float), stream);

    k_hin<<<NN / 256, 256, 0, stream>>>(h, vn, batch, h_in, vnsum, has_vn);
    k_edge<<<NE / 256, 256, 0, stream>>>(h_in, edge_index, edge_attr,
                                         bond_emb + (size_t)l * 3 * 6 * DD, X);
    k_partA<<<NN / 256, 256, 0, stream>>>(X, h_in, W1 + (size_t)l * DD * HH,
                                          b1 + (size_t)l * HH, eps_gin + l, stats);
    k_bnfin<<<1, 32, 0, stream>>>(stats, bn1_g + (size_t)l * HH, bn1_b + (size_t)l * HH,
                                  HH, 1.0f / NN, SUM1, SQ1, SCALE1, SHIFT1);
    k_partB<<<NN / 256, 256, 0, stream>>>(X, Y, W1 + (size_t)l * DD * HH,
                                          b1 + (size_t)l * HH, W2 + (size_t)l * HH * DD,
                                          b2 + (size_t)l * DD, stats, stats);
    k_bnfin<<<1, 32, 0, stream>>>(stats, bno_g + (size_t)l * DD, bno_b + (size_t)l * DD,
                                  DD, 1.0f / NN, SUM2, SQ2, SCALE2, SHIFT2);
    k_partC<<<NN / 256, 256, 0, stream>>>(Y, h_in, h, stats, has_vn,
                                          (l == 2) ? out : nullptr);
    if (has_vn) {
      k_vnA<<<NG / 256, 256, 0, stream>>>(vnsum, vn, vt1, vnW1 + (size_t)l * DD * HH,
                                          vnb1 + (size_t)l * HH, stats);
      k_bnfin<<<1, 32, 0, stream>>>(stats, vnbn1_g + (size_t)l * HH,
                                    vnbn1_b + (size_t)l * HH, HH, 1.0f / NG,
                                    VSUM1, VSQ1, VSCALE1, VSHIFT1);
      k_vnB<<<NG / 256, 256, 0, stream>>>(vt1, vt2, vnW2 + (size_t)l * HH * DD,
                                          vnb2 + (size_t)l * DD, stats);
      k_bnfin<<<1, 32, 0, stream>>>(stats, vnbn2_g + (size_t)l * DD,
                                    vnbn2_b + (size_t)l * DD, DD, 1.0f / NG,
                                    VSUM2, VSQ2, VSCALE2, VSHIFT2);
      k_vnC<<<NG / 256, 256, 0, stream>>>(vt2, vn, stats);
    }
  }
}

// Round 3
// 4451.713 us; speedup vs baseline: 3.1713x; 3.1713x over previous
//
#include <hip/hip_runtime.h>

#define NN 1048576   // nodes
#define NE 8388608   // edges
#define NG 32768     // graphs
#define DD 9         // emb dim
#define HH 18        // hidden
#define BN_EPS 1e-5f

#define NPB 1024     // nodes per bucket
#define NB  1024     // buckets (NN/NPB)

// stats buffer offsets (floats)
#define SUM1    0
#define SQ1     18
#define SUM2    36
#define SQ2     45
#define SCALE1  54
#define SHIFT1  72
#define SCALE2  90
#define SHIFT2  99
#define VSUM1   108
#define VSQ1    126
#define VSUM2   144
#define VSQ2    153
#define VSCALE1 162
#define VSHIFT1 180
#define VSCALE2 198
#define VSHIFT2 207
#define STATS_FLOATS 256

__device__ __forceinline__ float waveReduce(float v) {
#pragma unroll
  for (int off = 32; off > 0; off >>= 1) v += __shfl_down(v, off, 64);
  return v;
}

// ---------------- binning (once per launch) ----------------

// count edges per dst-bucket
__global__ void k_count(const int* __restrict__ ei, int* __restrict__ bucket_count) {
  __shared__ int hist[NB];
  for (int i = threadIdx.x; i < NB; i += 256) hist[i] = 0;
  __syncthreads();
  const int CH = NE / 2048;  // 4096 edges per block
  int base = blockIdx.x * CH;
  for (int i = threadIdx.x; i < CH; i += 256) {
    int d = ei[NE + base + i];
    atomicAdd(&hist[d >> 10], 1);
  }
  __syncthreads();
  for (int i = threadIdx.x; i < NB; i += 256)
    if (hist[i]) atomicAdd(&bucket_count[i], hist[i]);
}

// exclusive scan of 1024 counts -> bucket_base (with sentinel), bucket_cursor
__global__ void k_scan(const int* __restrict__ bucket_count, int* __restrict__ bucket_base,
                       int* __restrict__ bucket_cursor) {
  __shared__ int s[NB];
  int tid = threadIdx.x;
  int c = bucket_count[tid];
  s[tid] = c;
  __syncthreads();
  for (int off = 1; off < NB; off <<= 1) {
    int v = (tid >= off) ? s[tid - off] : 0;
    __syncthreads();
    s[tid] += v;
    __syncthreads();
  }
  int excl = s[tid] - c;
  bucket_base[tid] = excl;
  bucket_cursor[tid] = excl;
  if (tid == NB - 1) bucket_base[NB] = s[tid];
}

// scatter packed edge records into bucket-contiguous array
// record: x = src; y = (dst_local << 9) | (a0 | a1<<3 | a2<<6)
__global__ void k_scatter(const int* __restrict__ ei, const int* __restrict__ ea,
                          int* __restrict__ bucket_cursor, uint2* __restrict__ binned) {
  __shared__ int hist[NB];
  __shared__ int lbase[NB];
  for (int i = threadIdx.x; i < NB; i += 256) hist[i] = 0;
  __syncthreads();
  const int CH = NE / 512;  // 16384 edges per block
  int base = blockIdx.x * CH;
  for (int i = threadIdx.x; i < CH; i += 256) {
    int d = ei[NE + base + i];
    atomicAdd(&hist[d >> 10], 1);
  }
  __syncthreads();
  for (int i = threadIdx.x; i < NB; i += 256) {
    int c = hist[i];
    lbase[i] = c ? atomicAdd(&bucket_cursor[i], c) : 0;
    hist[i] = 0;  // reuse as local cursor
  }
  __syncthreads();
  for (int i = threadIdx.x; i < CH; i += 256) {
    int e = base + i;
    int s = ei[e];
    int d = ei[NE + e];
    int a0 = ea[(size_t)e * 3 + 0];
    int a1 = ea[(size_t)e * 3 + 1];
    int a2 = ea[(size_t)e * 3 + 2];
    int b = d >> 10;
    int pos = lbase[b] + atomicAdd(&hist[b], 1);
    uint2 r;
    r.x = (unsigned)s;
    r.y = ((unsigned)(d & (NPB - 1)) << 9) | (unsigned)(a0 | (a1 << 3) | (a2 << 6));
    binned[pos] = r;
  }
}

// ---------------- per-layer kernels ----------------

// h[n,:] = sum_f atom_emb[f, x[n,f], :]   (into hbuf)
__global__ void k_atom(const float* __restrict__ atom_emb, const int* __restrict__ x,
                       float* __restrict__ h) {
  int n = blockIdx.x * 256 + threadIdx.x;
  int xi[9];
#pragma unroll
  for (int f = 0; f < 9; ++f) xi[f] = x[(size_t)n * 9 + f];
  float acc[DD] = {0.f,0.f,0.f,0.f,0.f,0.f,0.f,0.f,0.f};
#pragma unroll
  for (int f = 0; f < 9; ++f) {
    const float* row = atom_emb + ((size_t)f * 119 + xi[f]) * DD;
#pragma unroll
    for (int d = 0; d < DD; ++d) acc[d] += row[d];
  }
#pragma unroll
  for (int d = 0; d < DD; ++d) h[(size_t)n * DD + d] = acc[d];
}

// in-place: hbuf[n] += vn[batch[n]]; optionally vnsum[batch[n]] += hbuf[n]
__global__ void k_hin(float* __restrict__ hbuf, const float* __restrict__ vn,
                      const int* __restrict__ batch, float* __restrict__ vnsum,
                      int do_vnsum) {
  int n = blockIdx.x * 256 + threadIdx.x;
  int g = batch[n];
  float v[DD];
#pragma unroll
  for (int d = 0; d < DD; ++d) {
    v[d] = hbuf[(size_t)n * DD + d] + vn[(size_t)g * DD + d];
    hbuf[(size_t)n * DD + d] = v[d];
  }
  if (do_vnsum) {
#pragma unroll
    for (int d = 0; d < DD; ++d) atomicAdd(&vnsum[(size_t)g * DD + d], v[d]);
  }
}

// One block per bucket: LDS-aggregate messages, then fused partA epilogue:
// X = (1+eps)*h_in + aggr;  BN1 stats of (X @ W1 + b1)
__global__ void __launch_bounds__(256)
k_edge_agg(const float* __restrict__ hbuf, const uint2* __restrict__ binned,
           const int* __restrict__ bucket_base, const float* __restrict__ bond,
           const float* __restrict__ W1l, const float* __restrict__ b1l,
           const float* __restrict__ epsp, float* __restrict__ X,
           float* __restrict__ stats) {
  __shared__ float slice[NPB * DD];      // 36 KB
  __shared__ float B[3 * 6 * DD];        // 162
  __shared__ float sW1[DD * HH], sb1[HH];
  __shared__ float ssum[HH], ssq[HH];
  int tid = threadIdx.x;
  for (int i = tid; i < NPB * DD; i += 256) slice[i] = 0.f;
  for (int i = tid; i < 3 * 6 * DD; i += 256) B[i] = bond[i];
  for (int i = tid; i < DD * HH; i += 256) sW1[i] = W1l[i];
  if (tid < HH) { sb1[tid] = b1l[tid]; ssum[tid] = 0.f; ssq[tid] = 0.f; }
  __syncthreads();

  int b = blockIdx.x;
  int start = bucket_base[b];
  int end = bucket_base[b + 1];
  for (int i = start + tid; i < end; i += 256) {
    uint2 r = binned[i];
    int src = (int)r.x;
    int local = (int)(r.y >> 9);
    int at = (int)(r.y & 511u);
    const float* hs = hbuf + (size_t)src * DD;
    const float* b0 = B + (at & 7) * DD;
    const float* b1r = B + (6 + ((at >> 3) & 7)) * DD;
    const float* b2r = B + (12 + ((at >> 6) & 7)) * DD;
    float* sl = slice + local * DD;
#pragma unroll
    for (int d = 0; d < DD; ++d) {
      float m = hs[d] + b0[d] + b1r[d] + b2r[d];
      m = m > 0.f ? m : 0.f;
      atomicAdd(&sl[d], m);
    }
  }
  __syncthreads();

  // epilogue: 4 nodes per thread
  float eps1 = 1.0f + epsp[0];
  float psum[HH], psq[HH];
#pragma unroll
  for (int j = 0; j < HH; ++j) { psum[j] = 0.f; psq[j] = 0.f; }
  size_t n0 = (size_t)b * NPB;
#pragma unroll
  for (int k = 0; k < 4; ++k) {
    int node = k * 256 + tid;
    size_t n = n0 + node;
    float z[DD];
#pragma unroll
    for (int d = 0; d < DD; ++d) {
      z[d] = eps1 * hbuf[n * DD + d] + slice[node * DD + d];
      X[n * DD + d] = z[d];
    }
#pragma unroll
    for (int j = 0; j < HH; ++j) {
      float a = sb1[j];
#pragma unroll
      for (int d = 0; d < DD; ++d) a += z[d] * sW1[d * HH + j];
      psum[j] += a;
      psq[j] += a * a;
    }
  }
  int lane0 = ((tid & 63) == 0);
#pragma unroll
  for (int j = 0; j < HH; ++j) {
    float rs = waveReduce(psum[j]);
    float rq = waveReduce(psq[j]);
    if (lane0) { atomicAdd(&ssum[j], rs); atomicAdd(&ssq[j], rq); }
  }
  __syncthreads();
  if (tid < HH) {
    atomicAdd(&stats[SUM1 + tid], ssum[tid]);
    atomicAdd(&stats[SQ1 + tid], ssq[tid]);
  }
}

// generic BN finalize
__global__ void k_bnfin(float* __restrict__ stats, const float* __restrict__ g,
                        const float* __restrict__ b, int C, float invN,
                        int sum_off, int sq_off, int scale_off, int shift_off) {
  int c = threadIdx.x;
  if (c >= C) return;
  float mean = stats[sum_off + c] * invN;
  float var = stats[sq_off + c] * invN - mean * mean;
  float inv = rsqrtf(var + BN_EPS);
  float sc = g[c] * inv;
  stats[scale_off + c] = sc;
  stats[shift_off + c] = b[c] - mean * sc;
}

// in-place X: z2 = relu(bn1(z@W1+b1)) @ W2 + b2;  BN2 stats
__global__ void k_partB(float* __restrict__ X,
                        const float* __restrict__ W1l, const float* __restrict__ b1l,
                        const float* __restrict__ W2l, const float* __restrict__ b2l,
                        float* __restrict__ stats) {
  __shared__ float sW1[DD * HH], sW2[HH * DD], sb1[HH], sb2[DD];
  __shared__ float sc1[HH], sh1[HH], ssum[DD], ssq[DD];
  for (int i = threadIdx.x; i < DD * HH; i += 256) sW1[i] = W1l[i];
  for (int i = threadIdx.x; i < HH * DD; i += 256) sW2[i] = W2l[i];
  if (threadIdx.x < HH) {
    sb1[threadIdx.x] = b1l[threadIdx.x];
    sc1[threadIdx.x] = stats[SCALE1 + threadIdx.x];
    sh1[threadIdx.x] = stats[SHIFT1 + threadIdx.x];
  }
  if (threadIdx.x < DD) {
    sb2[threadIdx.x] = b2l[threadIdx.x];
    ssum[threadIdx.x] = 0.f;
    ssq[threadIdx.x] = 0.f;
  }
  __syncthreads();
  int n = blockIdx.x * 256 + threadIdx.x;
  float z[DD];
#pragma unroll
  for (int d = 0; d < DD; ++d) z[d] = X[(size_t)n * DD + d];
  float t[HH];
#pragma unroll
  for (int j = 0; j < HH; ++j) {
    float a = sb1[j];
#pragma unroll
    for (int d = 0; d < DD; ++d) a += z[d] * sW1[d * HH + j];
    a = a * sc1[j] + sh1[j];
    t[j] = a > 0.f ? a : 0.f;
  }
  int lane0 = ((threadIdx.x & 63) == 0);
#pragma unroll
  for (int d = 0; d < DD; ++d) {
    float a = sb2[d];
#pragma unroll
    for (int j = 0; j < HH; ++j) a += t[j] * sW2[j * DD + d];
    X[(size_t)n * DD + d] = a;
    float rs = waveReduce(a);
    float rq = waveReduce(a * a);
    if (lane0) { atomicAdd(&ssum[d], rs); atomicAdd(&ssq[d], rq); }
  }
  __syncthreads();
  if (threadIdx.x < DD) {
    atomicAdd(&stats[SUM2 + threadIdx.x], ssum[threadIdx.x]);
    atomicAdd(&stats[SQ2 + threadIdx.x], ssq[threadIdx.x]);
  }
}

// in-place hbuf: h_new = bn2(z2) [relu] + h_in; last layer: accumulate col sums
__global__ void k_partC(const float* __restrict__ X, float* __restrict__ hbuf,
                        const float* __restrict__ stats, int do_relu,
                        float* __restrict__ out) {
  __shared__ float sc[DD], sh[DD], ssum[DD];
  if (threadIdx.x < DD) {
    sc[threadIdx.x] = stats[SCALE2 + threadIdx.x];
    sh[threadIdx.x] = stats[SHIFT2 + threadIdx.x];
    ssum[threadIdx.x] = 0.f;
  }
  __syncthreads();
  int n = blockIdx.x * 256 + threadIdx.x;
  float hv[DD];
#pragma unroll
  for (int d = 0; d < DD; ++d) {
    float z = X[(size_t)n * DD + d] * sc[d] + sh[d];
    if (do_relu) z = z > 0.f ? z : 0.f;
    hv[d] = z + hbuf[(size_t)n * DD + d];
    hbuf[(size_t)n * DD + d] = hv[d];
  }
  if (out != nullptr) {
    int lane0 = ((threadIdx.x & 63) == 0);
#pragma unroll
    for (int d = 0; d < DD; ++d) {
      float r = waveReduce(hv[d]);
      if (lane0) atomicAdd(&ssum[d], r);
    }
    __syncthreads();
    if (threadIdx.x < DD) atomicAdd(&out[threadIdx.x], ssum[threadIdx.x]);
  }
}

// ---------------- virtual-node MLP ----------------

__global__ void k_vnA(const float* __restrict__ vnsum, const float* __restrict__ vn,
                      float* __restrict__ vt1, const float* __restrict__ W1l,
                      const float* __restrict__ b1l, float* __restrict__ stats) {
  __shared__ float sW[DD * HH], sb[HH], ssum[HH], ssq[HH];
  for (int i = threadIdx.x; i < DD * HH; i += 256) sW[i] = W1l[i];
  if (threadIdx.x < HH) {
    sb[threadIdx.x] = b1l[threadIdx.x];
    ssum[threadIdx.x] = 0.f;
    ssq[threadIdx.x] = 0.f;
  }
  __syncthreads();
  int g = blockIdx.x * 256 + threadIdx.x;
  float r[DD];
#pragma unroll
  for (int d = 0; d < DD; ++d)
    r[d] = vnsum[(size_t)g * DD + d] + vn[(size_t)g * DD + d];
  int lane0 = ((threadIdx.x & 63) == 0);
#pragma unroll
  for (int j = 0; j < HH; ++j) {
    float a = sb[j];
#pragma unroll
    for (int d = 0; d < DD; ++d) a += r[d] * sW[d * HH + j];
    vt1[(size_t)g * HH + j] = a;
    float rs = waveReduce(a);
    float rq = waveReduce(a * a);
    if (lane0) { atomicAdd(&ssum[j], rs); atomicAdd(&ssq[j], rq); }
  }
  __syncthreads();
  if (threadIdx.x < HH) {
    atomicAdd(&stats[VSUM1 + threadIdx.x], ssum[threadIdx.x]);
    atomicAdd(&stats[VSQ1 + threadIdx.x], ssq[threadIdx.x]);
  }
}

__global__ void k_vnB(const float* __restrict__ vt1, float* __restrict__ vt2,
                      const float* __restrict__ W2l, const float* __restrict__ b2l,
                      float* __restrict__ stats) {
  __shared__ float sW2[HH * DD], sb2[DD], sc1[HH], sh1[HH], ssum[DD], ssq[DD];
  for (int i = threadIdx.x; i < HH * DD; i += 256) sW2[i] = W2l[i];
  if (threadIdx.x < HH) {
    sc1[threadIdx.x] = stats[VSCALE1 + threadIdx.x];
    sh1[threadIdx.x] = stats[VSHIFT1 + threadIdx.x];
  }
  if (threadIdx.x < DD) {
    sb2[threadIdx.x] = b2l[threadIdx.x];
    ssum[threadIdx.x] = 0.f;
    ssq[threadIdx.x] = 0.f;
  }
  __syncthreads();
  int g = blockIdx.x * 256 + threadIdx.x;
  float t[HH];
#pragma unroll
  for (int j = 0; j < HH; ++j) {
    float a = vt1[(size_t)g * HH + j] * sc1[j] + sh1[j];
    t[j] = a > 0.f ? a : 0.f;
  }
  int lane0 = ((threadIdx.x & 63) == 0);
#pragma unroll
  for (int d = 0; d < DD; ++d) {
    float a = sb2[d];
#pragma unroll
    for (int j = 0; j < HH; ++j) a += t[j] * sW2[j * DD + d];
    vt2[(size_t)g * DD + d] = a;
    float rs = waveReduce(a);
    float rq = waveReduce(a * a);
    if (lane0) { atomicAdd(&ssum[d], rs); atomicAdd(&ssq[d], rq); }
  }
  __syncthreads();
  if (threadIdx.x < DD) {
    atomicAdd(&stats[VSUM2 + threadIdx.x], ssum[threadIdx.x]);
    atomicAdd(&stats[VSQ2 + threadIdx.x], ssq[threadIdx.x]);
  }
}

__global__ void k_vnC(const float* __restrict__ vt2, float* __restrict__ vn,
                      const float* __restrict__ stats) {
  __shared__ float sc[DD], sh[DD];
  if (threadIdx.x < DD) {
    sc[threadIdx.x] = stats[VSCALE2 + threadIdx.x];
    sh[threadIdx.x] = stats[VSHIFT2 + threadIdx.x];
  }
  __syncthreads();
  int g = blockIdx.x * 256 + threadIdx.x;
#pragma unroll
  for (int d = 0; d < DD; ++d) {
    float v = vt2[(size_t)g * DD + d] * sc[d] + sh[d];
    v = v > 0.f ? v : 0.f;
    vn[(size_t)g * DD + d] += v;
  }
}

extern "C" void kernel_launch(void* const* d_in, const int* in_sizes, int n_in,
                              void* d_out, int out_size, void* d_ws, size_t ws_size,
                              hipStream_t stream) {
  const float* atom_emb = (const float*)d_in[0];
  const float* bond_emb = (const float*)d_in[1];
  const float* eps_gin  = (const float*)d_in[2];
  const float* W1   = (const float*)d_in[3];
  const float* b1   = (const float*)d_in[4];
  const float* bn1_g = (const float*)d_in[5];
  const float* bn1_b = (const float*)d_in[6];
  const float* W2   = (const float*)d_in[7];
  const float* b2   = (const float*)d_in[8];
  const float* bno_g = (const float*)d_in[9];
  const float* bno_b = (const float*)d_in[10];
  const float* vnW1 = (const float*)d_in[11];
  const float* vnb1 = (const float*)d_in[12];
  const float* vnbn1_g = (const float*)d_in[13];
  const float* vnbn1_b = (const float*)d_in[14];
  const float* vnW2 = (const float*)d_in[15];
  const float* vnb2 = (const float*)d_in[16];
  const float* vnbn2_g = (const float*)d_in[17];
  const float* vnbn2_b = (const float*)d_in[18];
  const int* x          = (const int*)d_in[19];
  const int* edge_index = (const int*)d_in[20];
  const int* edge_attr  = (const int*)d_in[21];
  const int* batch      = (const int*)d_in[22];
  float* out = (float*)d_out;

  // workspace layout (floats) — ~147 MB total
  float* hbuf  = (float*)d_ws;                       // NN*DD (h / h_in in place)
  float* X     = hbuf + (size_t)NN * DD;             // NN*DD (aggr->z->z2)
  uint2* binned = (uint2*)(X + (size_t)NN * DD);     // NE uint2
  float* after = (float*)(binned + (size_t)NE);
  float* vn    = after;                              // NG*DD
  float* vnsum = vn    + (size_t)NG * DD;
  float* vt1   = vnsum + (size_t)NG * DD;            // NG*HH
  float* vt2   = vt1   + (size_t)NG * HH;
  float* stats = vt2   + (size_t)NG * DD;
  int* bucket_count  = (int*)(stats + STATS_FLOATS);
  int* bucket_base   = bucket_count + NB;            // NB+1
  int* bucket_cursor = bucket_base + NB + 1;

  // ---- one-time binning ----
  (void)hipMemsetAsync(bucket_count, 0, NB * sizeof(int), stream);
  k_count<<<2048, 256, 0, stream>>>(edge_index, bucket_count);
  k_scan<<<1, NB, 0, stream>>>(bucket_count, bucket_base, bucket_cursor);
  k_scatter<<<512, 256, 0, stream>>>(edge_index, edge_attr, bucket_cursor, binned);

  (void)hipMemsetAsync(vn, 0, (size_t)NG * DD * sizeof(float), stream);
  (void)hipMemsetAsync(out, 0, (size_t)DD * sizeof(float), stream);
  k_atom<<<NN / 256, 256, 0, stream>>>(atom_emb, x, hbuf);

  for (int l = 0; l < 3; ++l) {
    int has_vn = (l < 2) ? 1 : 0;
    (void)hipMemsetAsync(stats, 0, STATS_FLOATS * sizeof(float), stream);
    if (has_vn)
      (void)hipMemsetAsync(vnsum, 0, (size_t)NG * DD * sizeof(float), stream);

    k_hin<<<NN / 256, 256, 0, stream>>>(hbuf, vn, batch, vnsum, has_vn);
    k_edge_agg<<<NB, 256, 0, stream>>>(hbuf, binned, bucket_base,
                                       bond_emb + (size_t)l * 3 * 6 * DD,
                                       W1 + (size_t)l * DD * HH, b1 + (size_t)l * HH,
                                       eps_gin + l, X, stats);
    k_bnfin<<<1, 32, 0, stream>>>(stats, bn1_g + (size_t)l * HH, bn1_b + (size_t)l * HH,
                                  HH, 1.0f / NN, SUM1, SQ1, SCALE1, SHIFT1);
    k_partB<<<NN / 256, 256, 0, stream>>>(X, W1 + (size_t)l * DD * HH,
                                          b1 + (size_t)l * HH, W2 + (size_t)l * HH * DD,
                                          b2 + (size_t)l * DD, stats);
    k_bnfin<<<1, 32, 0, stream>>>(stats, bno_g + (size_t)l * DD, bno_b + (size_t)l * DD,
                                  DD, 1.0f / NN, SUM2, SQ2, SCALE2, SHIFT2);
    k_partC<<<NN / 256, 256, 0, stream>>>(X, hbuf, stats, has_vn,
                                          (l == 2) ? out : nullptr);
    if (has_vn) {
      k_vnA<<<NG / 256, 256, 0, stream>>>(vnsum, vn, vt1, vnW1 + (size_t)l * DD * HH,
                                          vnb1 + (size_t)l * HH, stats);
      k_bnfin<<<1, 32, 0, stream>>>(stats, vnbn1_g + (size_t)l * HH,
                                    vnbn1_b + (size_t)l * HH, HH, 1.0f / NG,
                                    VSUM1, VSQ1, VSCALE1, VSHIFT1);
      k_vnB<<<NG / 256, 256, 0, stream>>>(vt1, vt2, vnW2 + (size_t)l * HH * DD,
                                          vnb2 + (size_t)l * DD, stats);
      k_bnfin<<<1, 32, 0, stream>>>(stats, vnbn2_g + (size_t)l * DD,
                                    vnbn2_b + (size_t)l * DD, DD, 1.0f / NG,
                                    VSUM2, VSQ2, VSCALE2, VSHIFT2);
      k_vnC<<<NG / 256, 256, 0, stream>>>(vt2, vn, stats);
    }
  }
}

// Round 4
// 3178.938 us; speedup vs baseline: 4.4410x; 1.4004x over previous
//
#include <hip/hip_runtime.h>

#define NN 1048576   // nodes
#define NE 8388608   // edges
#define NG 32768     // graphs
#define DD 9         // emb dim
#define SNN 12       // padded row stride (48B, 16B-aligned)
#define HH 18        // hidden
#define BN_EPS 1e-5f

#define NPB 1024     // nodes per bucket
#define NB  1024     // buckets (NN/NPB)

// stats buffer offsets (floats)
#define SUM1    0
#define SQ1     18
#define SUM2    36
#define SQ2     45
#define SCALE1  54
#define SHIFT1  72
#define SCALE2  90
#define SHIFT2  99
#define VSUM1   108
#define VSQ1    126
#define VSUM2   144
#define VSQ2    153
#define VSCALE1 162
#define VSHIFT1 180
#define VSCALE2 198
#define VSHIFT2 207
#define STATS_FLOATS 256

__device__ __forceinline__ float waveReduce(float v) {
#pragma unroll
  for (int off = 32; off > 0; off >>= 1) v += __shfl_down(v, off, 64);
  return v;
}

// ---------------- binning (once per launch) ----------------

__global__ void k_count(const int* __restrict__ ei, int* __restrict__ bucket_count) {
  __shared__ int hist[NB];
  for (int i = threadIdx.x; i < NB; i += 256) hist[i] = 0;
  __syncthreads();
  const int CH = NE / 2048;
  int base = blockIdx.x * CH;
  for (int i = threadIdx.x; i < CH; i += 256) {
    int d = ei[NE + base + i];
    atomicAdd(&hist[d >> 10], 1);
  }
  __syncthreads();
  for (int i = threadIdx.x; i < NB; i += 256)
    if (hist[i]) atomicAdd(&bucket_count[i], hist[i]);
}

__global__ void k_scan(const int* __restrict__ bucket_count, int* __restrict__ bucket_base,
                       int* __restrict__ bucket_cursor) {
  __shared__ int s[NB];
  int tid = threadIdx.x;
  int c = bucket_count[tid];
  s[tid] = c;
  __syncthreads();
  for (int off = 1; off < NB; off <<= 1) {
    int v = (tid >= off) ? s[tid - off] : 0;
    __syncthreads();
    s[tid] += v;
    __syncthreads();
  }
  int excl = s[tid] - c;
  bucket_base[tid] = excl;
  bucket_cursor[tid] = excl;
  if (tid == NB - 1) bucket_base[NB] = s[tid];
}

// scatter: bsrc[pos]=src; bmeta[pos]=(dst_local<<3)|(a0|a1<<1|a2<<2)  (attrs are {0,1})
__global__ void k_scatter(const int* __restrict__ ei, const int* __restrict__ ea,
                          int* __restrict__ bucket_cursor, int* __restrict__ bsrc,
                          unsigned short* __restrict__ bmeta) {
  __shared__ int hist[NB];
  __shared__ int lbase[NB];
  for (int i = threadIdx.x; i < NB; i += 256) hist[i] = 0;
  __syncthreads();
  const int CH = NE / 512;
  int base = blockIdx.x * CH;
  for (int i = threadIdx.x; i < CH; i += 256) {
    int d = ei[NE + base + i];
    atomicAdd(&hist[d >> 10], 1);
  }
  __syncthreads();
  for (int i = threadIdx.x; i < NB; i += 256) {
    int c = hist[i];
    lbase[i] = c ? atomicAdd(&bucket_cursor[i], c) : 0;
    hist[i] = 0;
  }
  __syncthreads();
  for (int i = threadIdx.x; i < CH; i += 256) {
    int e = base + i;
    int s = ei[e];
    int d = ei[NE + e];
    int a0 = ea[(size_t)e * 3 + 0] & 1;
    int a1 = ea[(size_t)e * 3 + 1] & 1;
    int a2 = ea[(size_t)e * 3 + 2] & 1;
    int b = d >> 10;
    int pos = lbase[b] + atomicAdd(&hist[b], 1);
    bsrc[pos] = s;
    bmeta[pos] = (unsigned short)(((d & (NPB - 1)) << 3) | (a0 | (a1 << 1) | (a2 << 2)));
  }
}

// ---------------- per-layer kernels ----------------

// h[n,:] = sum_f atom_emb[f, x[n,f], :]  (padded stride SNN)
__global__ void k_atom(const float* __restrict__ atom_emb, const int* __restrict__ x,
                       float* __restrict__ h) {
  int n = blockIdx.x * 256 + threadIdx.x;
  int xi[9];
#pragma unroll
  for (int f = 0; f < 9; ++f) xi[f] = x[(size_t)n * 9 + f];
  float acc[DD] = {0.f,0.f,0.f,0.f,0.f,0.f,0.f,0.f,0.f};
#pragma unroll
  for (int f = 0; f < 9; ++f) {
    const float* row = atom_emb + ((size_t)f * 119 + xi[f]) * DD;
#pragma unroll
    for (int d = 0; d < DD; ++d) acc[d] += row[d];
  }
  float4* o = (float4*)(h + (size_t)n * SNN);
  o[0] = make_float4(acc[0], acc[1], acc[2], acc[3]);
  o[1] = make_float4(acc[4], acc[5], acc[6], acc[7]);
  o[2] = make_float4(acc[8], 0.f, 0.f, 0.f);
}

// hbuf[n] += vn[batch[n]] (in place); if do_vnsum: segmented-reduce into vnsum
__global__ void k_hin(float* __restrict__ hbuf, const float* __restrict__ vn,
                      const int* __restrict__ batch, float* __restrict__ vnsum,
                      int do_vnsum) {
  int n = blockIdx.x * 256 + threadIdx.x;
  int g = batch[n];
  float4* hr = (float4*)(hbuf + (size_t)n * SNN);
  float4 A = hr[0], B = hr[1], C = hr[2];
  float v[DD] = {A.x, A.y, A.z, A.w, B.x, B.y, B.z, B.w, C.x};
#pragma unroll
  for (int d = 0; d < DD; ++d) v[d] += vn[(size_t)g * DD + d];
  hr[0] = make_float4(v[0], v[1], v[2], v[3]);
  hr[1] = make_float4(v[4], v[5], v[6], v[7]);
  hr[2] = make_float4(v[8], 0.f, 0.f, 0.f);
  if (do_vnsum) {
    int lane = threadIdx.x & 63;
    float s[DD];
#pragma unroll
    for (int d = 0; d < DD; ++d) s[d] = v[d];
    // segmented inclusive scan over sorted graph ids (runs are contiguous)
#pragma unroll
    for (int st = 1; st < 64; st <<= 1) {
      int gu = __shfl_up(g, st, 64);
      bool ok = (lane >= st) && (gu == g);
#pragma unroll
      for (int d = 0; d < DD; ++d) {
        float vu = __shfl_up(s[d], st, 64);
        if (ok) s[d] += vu;
      }
    }
    int gn = __shfl_down(g, 1, 64);
    bool tail = (lane == 63) || (gn != g);
    if (tail) {
#pragma unroll
      for (int d = 0; d < DD; ++d) atomicAdd(&vnsum[(size_t)g * DD + d], s[d]);
    }
  }
}

// One block per bucket: LDS-aggregate, fused epilogue:
// X = (1+eps)*h_in + aggr (stride SNN);  BN1 stats of (X @ W1 + b1)
__global__ void __launch_bounds__(256)
k_edge_agg(const float* __restrict__ hbuf, const int* __restrict__ bsrc,
           const unsigned short* __restrict__ bmeta,
           const int* __restrict__ bucket_base, const float* __restrict__ bond,
           const float* __restrict__ W1l, const float* __restrict__ b1l,
           const float* __restrict__ epsp, float* __restrict__ X,
           float* __restrict__ stats) {
  __shared__ float slice[NPB * DD];      // 36 KB
  __shared__ float B[3 * 6 * DD];        // raw bond table
  __shared__ float comb[8 * SNN];        // precombined bond sums (attrs in {0,1})
  __shared__ float sW1[DD * HH], sb1[HH];
  __shared__ float ssum[HH], ssq[HH];
  int tid = threadIdx.x;
  for (int i = tid; i < NPB * DD; i += 256) slice[i] = 0.f;
  for (int i = tid; i < 3 * 6 * DD; i += 256) B[i] = bond[i];
  for (int i = tid; i < DD * HH; i += 256) sW1[i] = W1l[i];
  if (tid < HH) { sb1[tid] = b1l[tid]; ssum[tid] = 0.f; ssq[tid] = 0.f; }
  __syncthreads();
  if (tid < 8 * DD) {
    int c = tid / DD, d = tid % DD;
    comb[c * SNN + d] = B[(0 * 6 + (c & 1)) * DD + d] +
                        B[(1 * 6 + ((c >> 1) & 1)) * DD + d] +
                        B[(2 * 6 + ((c >> 2) & 1)) * DD + d];
  }
  __syncthreads();

  int b = blockIdx.x;
  int start = bucket_base[b];
  int end = bucket_base[b + 1];
  for (int i = start + tid; i < end; i += 256) {
    int src = bsrc[i];
    unsigned m = bmeta[i];
    const float4* hs = (const float4*)(hbuf + (size_t)src * SNN);
    float4 A = hs[0], Bv = hs[1], Cv = hs[2];
    float hv[DD] = {A.x, A.y, A.z, A.w, Bv.x, Bv.y, Bv.z, Bv.w, Cv.x};
    const float* cb = comb + (m & 7u) * SNN;
    float* sl = slice + (m >> 3) * DD;
#pragma unroll
    for (int d = 0; d < DD; ++d) {
      float msg = hv[d] + cb[d];
      msg = msg > 0.f ? msg : 0.f;
      atomicAdd(&sl[d], msg);
    }
  }
  __syncthreads();

  // epilogue: 4 nodes per thread
  float eps1 = 1.0f + epsp[0];
  float psum[HH], psq[HH];
#pragma unroll
  for (int j = 0; j < HH; ++j) { psum[j] = 0.f; psq[j] = 0.f; }
  size_t n0 = (size_t)b * NPB;
#pragma unroll
  for (int k = 0; k < 4; ++k) {
    int node = k * 256 + tid;
    size_t n = n0 + node;
    const float4* hr = (const float4*)(hbuf + n * SNN);
    float4 A = hr[0], Bv = hr[1], Cv = hr[2];
    float hv[DD] = {A.x, A.y, A.z, A.w, Bv.x, Bv.y, Bv.z, Bv.w, Cv.x};
    float z[DD];
#pragma unroll
    for (int d = 0; d < DD; ++d) z[d] = eps1 * hv[d] + slice[node * DD + d];
    float4* xo = (float4*)(X + n * SNN);
    xo[0] = make_float4(z[0], z[1], z[2], z[3]);
    xo[1] = make_float4(z[4], z[5], z[6], z[7]);
    xo[2] = make_float4(z[8], 0.f, 0.f, 0.f);
#pragma unroll
    for (int j = 0; j < HH; ++j) {
      float a = sb1[j];
#pragma unroll
      for (int d = 0; d < DD; ++d) a += z[d] * sW1[d * HH + j];
      psum[j] += a;
      psq[j] += a * a;
    }
  }
  int lane0 = ((tid & 63) == 0);
#pragma unroll
  for (int j = 0; j < HH; ++j) {
    float rs = waveReduce(psum[j]);
    float rq = waveReduce(psq[j]);
    if (lane0) { atomicAdd(&ssum[j], rs); atomicAdd(&ssq[j], rq); }
  }
  __syncthreads();
  if (tid < HH) {
    atomicAdd(&stats[SUM1 + tid], ssum[tid]);
    atomicAdd(&stats[SQ1 + tid], ssq[tid]);
  }
}

// generic BN finalize
__global__ void k_bnfin(float* __restrict__ stats, const float* __restrict__ g,
                        const float* __restrict__ b, int C, float invN,
                        int sum_off, int sq_off, int scale_off, int shift_off) {
  int c = threadIdx.x;
  if (c >= C) return;
  float mean = stats[sum_off + c] * invN;
  float var = stats[sq_off + c] * invN - mean * mean;
  float inv = rsqrtf(var + BN_EPS);
  float sc = g[c] * inv;
  stats[scale_off + c] = sc;
  stats[shift_off + c] = b[c] - mean * sc;
}

// in-place X (stride SNN): z2 = relu(bn1(z@W1+b1)) @ W2 + b2;  BN2 stats
__global__ void k_partB(float* __restrict__ X,
                        const float* __restrict__ W1l, const float* __restrict__ b1l,
                        const float* __restrict__ W2l, const float* __restrict__ b2l,
                        float* __restrict__ stats) {
  __shared__ float sW1[DD * HH], sW2[HH * DD], sb1[HH], sb2[DD];
  __shared__ float sc1[HH], sh1[HH], ssum[DD], ssq[DD];
  for (int i = threadIdx.x; i < DD * HH; i += 256) sW1[i] = W1l[i];
  for (int i = threadIdx.x; i < HH * DD; i += 256) sW2[i] = W2l[i];
  if (threadIdx.x < HH) {
    sb1[threadIdx.x] = b1l[threadIdx.x];
    sc1[threadIdx.x] = stats[SCALE1 + threadIdx.x];
    sh1[threadIdx.x] = stats[SHIFT1 + threadIdx.x];
  }
  if (threadIdx.x < DD) {
    sb2[threadIdx.x] = b2l[threadIdx.x];
    ssum[threadIdx.x] = 0.f;
    ssq[threadIdx.x] = 0.f;
  }
  __syncthreads();
  int n = blockIdx.x * 256 + threadIdx.x;
  float4* xr = (float4*)(X + (size_t)n * SNN);
  float4 A = xr[0], B = xr[1], C = xr[2];
  float z[DD] = {A.x, A.y, A.z, A.w, B.x, B.y, B.z, B.w, C.x};
  float t[HH];
#pragma unroll
  for (int j = 0; j < HH; ++j) {
    float a = sb1[j];
#pragma unroll
    for (int d = 0; d < DD; ++d) a += z[d] * sW1[d * HH + j];
    a = a * sc1[j] + sh1[j];
    t[j] = a > 0.f ? a : 0.f;
  }
  float z2[DD];
  int lane0 = ((threadIdx.x & 63) == 0);
#pragma unroll
  for (int d = 0; d < DD; ++d) {
    float a = sb2[d];
#pragma unroll
    for (int j = 0; j < HH; ++j) a += t[j] * sW2[j * DD + d];
    z2[d] = a;
    float rs = waveReduce(a);
    float rq = waveReduce(a * a);
    if (lane0) { atomicAdd(&ssum[d], rs); atomicAdd(&ssq[d], rq); }
  }
  xr[0] = make_float4(z2[0], z2[1], z2[2], z2[3]);
  xr[1] = make_float4(z2[4], z2[5], z2[6], z2[7]);
  xr[2] = make_float4(z2[8], 0.f, 0.f, 0.f);
  __syncthreads();
  if (threadIdx.x < DD) {
    atomicAdd(&stats[SUM2 + threadIdx.x], ssum[threadIdx.x]);
    atomicAdd(&stats[SQ2 + threadIdx.x], ssq[threadIdx.x]);
  }
}

// in-place hbuf: h_new = bn2(z2) [relu] + h_in; last layer: accumulate col sums
__global__ void k_partC(const float* __restrict__ X, float* __restrict__ hbuf,
                        const float* __restrict__ stats, int do_relu,
                        float* __restrict__ out) {
  __shared__ float sc[DD], sh[DD], ssum[DD];
  if (threadIdx.x < DD) {
    sc[threadIdx.x] = stats[SCALE2 + threadIdx.x];
    sh[threadIdx.x] = stats[SHIFT2 + threadIdx.x];
    ssum[threadIdx.x] = 0.f;
  }
  __syncthreads();
  int n = blockIdx.x * 256 + threadIdx.x;
  const float4* xr = (const float4*)(X + (size_t)n * SNN);
  float4 XA = xr[0], XB = xr[1], XC = xr[2];
  float zv[DD] = {XA.x, XA.y, XA.z, XA.w, XB.x, XB.y, XB.z, XB.w, XC.x};
  float4* hr = (float4*)(hbuf + (size_t)n * SNN);
  float4 HA = hr[0], HB = hr[1], HC = hr[2];
  float hi[DD] = {HA.x, HA.y, HA.z, HA.w, HB.x, HB.y, HB.z, HB.w, HC.x};
  float hv[DD];
#pragma unroll
  for (int d = 0; d < DD; ++d) {
    float z = zv[d] * sc[d] + sh[d];
    if (do_relu) z = z > 0.f ? z : 0.f;
    hv[d] = z + hi[d];
  }
  hr[0] = make_float4(hv[0], hv[1], hv[2], hv[3]);
  hr[1] = make_float4(hv[4], hv[5], hv[6], hv[7]);
  hr[2] = make_float4(hv[8], 0.f, 0.f, 0.f);
  if (out != nullptr) {
    int lane0 = ((threadIdx.x & 63) == 0);
#pragma unroll
    for (int d = 0; d < DD; ++d) {
      float r = waveReduce(hv[d]);
      if (lane0) atomicAdd(&ssum[d], r);
    }
    __syncthreads();
    if (threadIdx.x < DD) atomicAdd(&out[threadIdx.x], ssum[threadIdx.x]);
  }
}

// ---------------- virtual-node MLP ----------------

__global__ void k_vnA(const float* __restrict__ vnsum, const float* __restrict__ vn,
                      float* __restrict__ vt1, const float* __restrict__ W1l,
                      const float* __restrict__ b1l, float* __restrict__ stats) {
  __shared__ float sW[DD * HH], sb[HH], ssum[HH], ssq[HH];
  for (int i = threadIdx.x; i < DD * HH; i += 256) sW[i] = W1l[i];
  if (threadIdx.x < HH) {
    sb[threadIdx.x] = b1l[threadIdx.x];
    ssum[threadIdx.x] = 0.f;
    ssq[threadIdx.x] = 0.f;
  }
  __syncthreads();
  int g = blockIdx.x * 256 + threadIdx.x;
  float r[DD];
#pragma unroll
  for (int d = 0; d < DD; ++d)
    r[d] = vnsum[(size_t)g * DD + d] + vn[(size_t)g * DD + d];
  int lane0 = ((threadIdx.x & 63) == 0);
#pragma unroll
  for (int j = 0; j < HH; ++j) {
    float a = sb[j];
#pragma unroll
    for (int d = 0; d < DD; ++d) a += r[d] * sW[d * HH + j];
    vt1[(size_t)g * HH + j] = a;
    float rs = waveReduce(a);
    float rq = waveReduce(a * a);
    if (lane0) { atomicAdd(&ssum[j], rs); atomicAdd(&ssq[j], rq); }
  }
  __syncthreads();
  if (threadIdx.x < HH) {
    atomicAdd(&stats[VSUM1 + threadIdx.x], ssum[threadIdx.x]);
    atomicAdd(&stats[VSQ1 + threadIdx.x], ssq[threadIdx.x]);
  }
}

__global__ void k_vnB(const float* __restrict__ vt1, float* __restrict__ vt2,
                      const float* __restrict__ W2l, const float* __restrict__ b2l,
                      float* __restrict__ stats) {
  __shared__ float sW2[HH * DD], sb2[DD], sc1[HH], sh1[HH], ssum[DD], ssq[DD];
  for (int i = threadIdx.x; i < HH * DD; i += 256) sW2[i] = W2l[i];
  if (threadIdx.x < HH) {
    sc1[threadIdx.x] = stats[VSCALE1 + threadIdx.x];
    sh1[threadIdx.x] = stats[VSHIFT1 + threadIdx.x];
  }
  if (threadIdx.x < DD) {
    sb2[threadIdx.x] = b2l[threadIdx.x];
    ssum[threadIdx.x] = 0.f;
    ssq[threadIdx.x] = 0.f;
  }
  __syncthreads();
  int g = blockIdx.x * 256 + threadIdx.x;
  float t[HH];
#pragma unroll
  for (int j = 0; j < HH; ++j) {
    float a = vt1[(size_t)g * HH + j] * sc1[j] + sh1[j];
    t[j] = a > 0.f ? a : 0.f;
  }
  int lane0 = ((threadIdx.x & 63) == 0);
#pragma unroll
  for (int d = 0; d < DD; ++d) {
    float a = sb2[d];
#pragma unroll
    for (int j = 0; j < HH; ++j) a += t[j] * sW2[j * DD + d];
    vt2[(size_t)g * DD + d] = a;
    float rs = waveReduce(a);
    float rq = waveReduce(a * a);
    if (lane0) { atomicAdd(&ssum[d], rs); atomicAdd(&ssq[d], rq); }
  }
  __syncthreads();
  if (threadIdx.x < DD) {
    atomicAdd(&stats[VSUM2 + threadIdx.x], ssum[threadIdx.x]);
    atomicAdd(&stats[VSQ2 + threadIdx.x], ssq[threadIdx.x]);
  }
}

__global__ void k_vnC(const float* __restrict__ vt2, float* __restrict__ vn,
                      const float* __restrict__ stats) {
  __shared__ float sc[DD], sh[DD];
  if (threadIdx.x < DD) {
    sc[threadIdx.x] = stats[VSCALE2 + threadIdx.x];
    sh[threadIdx.x] = stats[VSHIFT2 + threadIdx.x];
  }
  __syncthreads();
  int g = blockIdx.x * 256 + threadIdx.x;
#pragma unroll
  for (int d = 0; d < DD; ++d) {
    float v = vt2[(size_t)g * DD + d] * sc[d] + sh[d];
    v = v > 0.f ? v : 0.f;
    vn[(size_t)g * DD + d] += v;
  }
}

extern "C" void kernel_launch(void* const* d_in, const int* in_sizes, int n_in,
                              void* d_out, int out_size, void* d_ws, size_t ws_size,
                              hipStream_t stream) {
  const float* atom_emb = (const float*)d_in[0];
  const float* bond_emb = (const float*)d_in[1];
  const float* eps_gin  = (const float*)d_in[2];
  const float* W1   = (const float*)d_in[3];
  const float* b1   = (const float*)d_in[4];
  const float* bn1_g = (const float*)d_in[5];
  const float* bn1_b = (const float*)d_in[6];
  const float* W2   = (const float*)d_in[7];
  const float* b2   = (const float*)d_in[8];
  const float* bno_g = (const float*)d_in[9];
  const float* bno_b = (const float*)d_in[10];
  const float* vnW1 = (const float*)d_in[11];
  const float* vnb1 = (const float*)d_in[12];
  const float* vnbn1_g = (const float*)d_in[13];
  const float* vnbn1_b = (const float*)d_in[14];
  const float* vnW2 = (const float*)d_in[15];
  const float* vnb2 = (const float*)d_in[16];
  const float* vnbn2_g = (const float*)d_in[17];
  const float* vnbn2_b = (const float*)d_in[18];
  const int* x          = (const int*)d_in[19];
  const int* edge_index = (const int*)d_in[20];
  const int* edge_attr  = (const int*)d_in[21];
  const int* batch      = (const int*)d_in[22];
  float* out = (float*)d_out;

  // workspace layout — ~157 MB total (same as proven R1 footprint)
  float* hbuf  = (float*)d_ws;                       // NN*SNN
  float* X     = hbuf + (size_t)NN * SNN;            // NN*SNN
  int* bsrc    = (int*)(X + (size_t)NN * SNN);       // NE ints
  unsigned short* bmeta = (unsigned short*)(bsrc + (size_t)NE);  // NE u16
  float* after = (float*)(bmeta + (size_t)NE);
  float* vn    = after;                              // NG*DD
  float* vnsum = vn    + (size_t)NG * DD;
  float* vt1   = vnsum + (size_t)NG * DD;            // NG*HH
  float* vt2   = vt1   + (size_t)NG * HH;
  float* stats = vt2   + (size_t)NG * DD;
  int* bucket_count  = (int*)(stats + STATS_FLOATS);
  int* bucket_base   = bucket_count + NB;            // NB+1
  int* bucket_cursor = bucket_base + NB + 1;

  // ---- one-time binning ----
  (void)hipMemsetAsync(bucket_count, 0, NB * sizeof(int), stream);
  k_count<<<2048, 256, 0, stream>>>(edge_index, bucket_count);
  k_scan<<<1, NB, 0, stream>>>(bucket_count, bucket_base, bucket_cursor);
  k_scatter<<<512, 256, 0, stream>>>(edge_index, edge_attr, bucket_cursor, bsrc, bmeta);

  (void)hipMemsetAsync(vn, 0, (size_t)NG * DD * sizeof(float), stream);
  (void)hipMemsetAsync(out, 0, (size_t)DD * sizeof(float), stream);
  k_atom<<<NN / 256, 256, 0, stream>>>(atom_emb, x, hbuf);

  for (int l = 0; l < 3; ++l) {
    int has_vn = (l < 2) ? 1 : 0;
    (void)hipMemsetAsync(stats, 0, STATS_FLOATS * sizeof(float), stream);
    if (has_vn)
      (void)hipMemsetAsync(vnsum, 0, (size_t)NG * DD * sizeof(float), stream);

    k_hin<<<NN / 256, 256, 0, stream>>>(hbuf, vn, batch, vnsum, has_vn);
    k_edge_agg<<<NB, 256, 0, stream>>>(hbuf, bsrc, bmeta, bucket_base,
                                       bond_emb + (size_t)l * 3 * 6 * DD,
                                       W1 + (size_t)l * DD * HH, b1 + (size_t)l * HH,
                                       eps_gin + l, X, stats);
    k_bnfin<<<1, 32, 0, stream>>>(stats, bn1_g + (size_t)l * HH, bn1_b + (size_t)l * HH,
                                  HH, 1.0f / NN, SUM1, SQ1, SCALE1, SHIFT1);
    k_partB<<<NN / 256, 256, 0, stream>>>(X, W1 + (size_t)l * DD * HH,
                                          b1 + (size_t)l * HH, W2 + (size_t)l * HH * DD,
                                          b2 + (size_t)l * DD, stats);
    k_bnfin<<<1, 32, 0, stream>>>(stats, bno_g + (size_t)l * DD, bno_b + (size_t)l * DD,
                                  DD, 1.0f / NN, SUM2, SQ2, SCALE2, SHIFT2);
    k_partC<<<NN / 256, 256, 0, stream>>>(X, hbuf, stats, has_vn,
                                          (l == 2) ? out : nullptr);
    if (has_vn) {
      k_vnA<<<NG / 256, 256, 0, stream>>>(vnsum, vn, vt1, vnW1 + (size_t)l * DD * HH,
                                          vnb1 + (size_t)l * HH, stats);
      k_bnfin<<<1, 32, 0, stream>>>(stats, vnbn1_g + (size_t)l * HH,
                                    vnbn1_b + (size_t)l * HH, HH, 1.0f / NG,
                                    VSUM1, VSQ1, VSCALE1, VSHIFT1);
      k_vnB<<<NG / 256, 256, 0, stream>>>(vt1, vt2, vnW2 + (size_t)l * HH * DD,
                                          vnb2 + (size_t)l * DD, stats);
      k_bnfin<<<1, 32, 0, stream>>>(stats, vnbn2_g + (size_t)l * DD,
                                    vnbn2_b + (size_t)l * DD, DD, 1.0f / NG,
                                    VSUM2, VSQ2, VSCALE2, VSHIFT2);
      k_vnC<<<NG / 256, 256, 0, stream>>>(vt2, vn, stats);
    }
  }
}